// Round 7
// baseline (355.410 us; speedup 1.0000x reference)
//
#include <hip/hip_runtime.h>
#include <stddef.h>

// ---------------------------------------------------------------------------
// CustomNet forward. Round 7: occupancy-first conv.
//  - conv: round-3 wave decomposition (proven fastest), h1 chunked into two
//    14-row halves -> LDS 26432 B; __launch_bounds__(512,8) pins VGPR<=64;
//    4 blocks/CU (thread cap). XOR-swizzled h1 chunk (A-read ~2-way).
//  - fc1/fc2: byte-identical round-3 kernels (replay-proven); k_fc1wpack
//    permutation updated to the new pooled word order.
// ---------------------------------------------------------------------------

#define NIMG 2048

typedef __attribute__((ext_vector_type(8))) short short8;
typedef __attribute__((ext_vector_type(4))) float f32x4;

__device__ inline ushort f2bf(float f) {
    unsigned u = __builtin_bit_cast(unsigned, f);
    unsigned r = (u + 0x7fff + ((u >> 16) & 1)) >> 16;   // RTNE, finite
    return (ushort)r;
}

// pack w2 [64][32][3][3] into per-lane 16x16x32 MFMA B-fragments (round-3):
// bfr[((nt*9 + kyx)*64 + lane)*8 + j] = bf16(w2[oc=nt*16+(lane&15)][ic=8*(lane>>4)+j][kyx])
__global__ void k_w2pack(const float* __restrict__ w2, ushort* __restrict__ bfr) {
    int i = blockIdx.x * 256 + threadIdx.x;
    if (i < 18432) {
        int j = i & 7;
        int l = (i >> 3) & 63;
        int t = i >> 9;
        int kyx = t % 9, nt = t / 9;
        int oc = nt * 16 + (l & 15);
        int ic = 8 * (l >> 4) + j;
        bfr[i] = f2bf(w2[oc * 288 + ic * 9 + kyx]);
    }
}

// Permute fc1_w columns into the conv kernel's pooled output order (bf16).
// kp = ((mt*2 + p)*64 + lane)*2 + j ->
//   oc = (2p+j)*16 + (lane&15); qid = mt*4 + (lane>>4); orig_k = oc*144 + qid.
__global__ void k_fc1wpack(const float* __restrict__ fc1_w, ushort* __restrict__ wp) {
    int idx = blockIdx.x * 256 + threadIdx.x;
    if (idx < 128 * 9216) {
        int n = idx / 9216, kp = idx % 9216;
        int j = kp & 1;
        int lane = (kp >> 1) & 63;
        int word = kp >> 7;
        int p = word & 1;
        int mt = word >> 1;
        int oc = (2 * p + j) * 16 + (lane & 15);
        int qid = mt * 4 + (lane >> 4);
        wp[idx] = f2bf(fc1_w[(size_t)n * 9216 + oc * 144 + qid]);
    }
}

// swizzled h1-chunk byte address for (local position q in [0,364), 16B-group g)
#define SWZB(q, g) ((((q) << 6) | ((g) << 4)) ^ (((q) & 14) << 3))

// LDS: [0, 23296) h1 chunk (14 rows x 26 pos x 32 ic bf16, swizzled);
//      [23296, 26432) xs (784 f32).
__launch_bounds__(512, 8)
__global__ void k_conv_fused(const float* __restrict__ x,
                             const float* __restrict__ w1,
                             const float* __restrict__ b1,
                             const ushort* __restrict__ bfr,
                             const float* __restrict__ b2,
                             ushort* __restrict__ pooled) {   // bf16, permuted k
    __shared__ char smem[26432];
    float* xs = (float*)(smem + 23296);
    const int tid = threadIdx.x;
    const int img = blockIdx.x;
    const int lane = tid & 63;
    const int w = tid >> 6;

    // ---- stage x ----
    const float* xg = x + (size_t)img * 784;
    for (int i = tid; i < 784; i += 512) xs[i] = xg[i];

    // ---- conv1 weights/bias (round-3 pattern; compiler manages residency) ----
    const int ocg = tid & 3;
    float w1r[72], b1r[8];
    #pragma unroll
    for (int j = 0; j < 8; j++) {
        b1r[j] = b1[ocg * 8 + j];
        #pragma unroll
        for (int q = 0; q < 9; q++) w1r[j * 9 + q] = w1[(ocg * 8 + j) * 9 + q];
    }

    const int p = w & 1;          // oc-tile pair
    const int g = w >> 1;         // m-group
    const int row = lane & 15;
    const int ic8 = lane >> 4;
    float b2v0 = b2[(2 * p) * 16 + row];
    float b2v1 = b2[(2 * p + 1) * 16 + row];
    uint* pg = (uint*)(pooled + (size_t)img * 9216);

    __syncthreads();   // xs ready

    #pragma unroll 1
    for (int c = 0; c < 2; c++) {
        if (c) __syncthreads();   // chunk-0 readers done before overwrite

        // ---- conv1 + relu -> swizzled h1 chunk (rows c*12 .. c*12+13) ----
        #pragma unroll
        for (int it = 0; it < 2; it++) {
            int pid = (tid >> 2) + it * 128;
            if (pid < 182) {
                int ry = pid / 13;
                int px2 = (pid - ry * 13) * 2;
                const float* xr = &xs[(c * 12 + ry) * 28 + px2];
                float xv[3][4];
                #pragma unroll
                for (int r = 0; r < 3; r++) {
                    float2 u = *(const float2*)&xr[r * 28];
                    float2 v = *(const float2*)&xr[r * 28 + 2];
                    xv[r][0] = u.x; xv[r][1] = u.y; xv[r][2] = v.x; xv[r][3] = v.y;
                }
                short8 pk0, pk1;
                #pragma unroll
                for (int j = 0; j < 8; j++) {
                    float s0 = b1r[j], s1 = b1r[j];
                    #pragma unroll
                    for (int ky = 0; ky < 3; ky++)
                        #pragma unroll
                        for (int kx = 0; kx < 3; kx++) {
                            float wv = w1r[j * 9 + ky * 3 + kx];
                            s0 = fmaf(wv, xv[ky][kx], s0);
                            s1 = fmaf(wv, xv[ky][kx + 1], s1);
                        }
                    pk0[j] = (short)f2bf(fmaxf(s0, 0.0f));
                    pk1[j] = (short)f2bf(fmaxf(s1, 0.0f));
                }
                int q0 = ry * 26 + px2;
                *(short8*)(smem + SWZB(q0, ocg)) = pk0;
                *(short8*)(smem + SWZB(q0 + 1, ocg)) = pk1;
            }
        }
        __syncthreads();

        // ---- conv2 MFMA on this chunk (18 local m-tiles) ----
        #pragma unroll 1
        for (int i = 0; i < 5; i++) {
            int mtl = g + 4 * i;
            if (mtl < 18) {
                int m = mtl * 16 + row;          // A-fragment row for this lane
                int qidl = m >> 2, de = m & 3;
                int py = qidl / 12, px = qidl - py * 12;
                int ql = (2 * py + (de >> 1)) * 26 + 2 * px + (de & 1);

                f32x4 acc0 = {0.f, 0.f, 0.f, 0.f};
                f32x4 acc1 = {0.f, 0.f, 0.f, 0.f};
                #pragma unroll
                for (int ky = 0; ky < 3; ky++)
                    #pragma unroll
                    for (int kx = 0; kx < 3; kx++) {
                        const int kyx = ky * 3 + kx;
                        short8 a = *(const short8*)(smem + SWZB(ql + ky * 26 + kx, ic8));
                        short8 bf0 = *(const short8*)&bfr[(((2 * p) * 9 + kyx) * 64 + lane) * 8];
                        short8 bf1 = *(const short8*)&bfr[(((2 * p + 1) * 9 + kyx) * 64 + lane) * 8];
                        acc0 = __builtin_amdgcn_mfma_f32_16x16x32_bf16(a, bf0, acc0, 0, 0, 0);
                        acc1 = __builtin_amdgcn_mfma_f32_16x16x32_bf16(a, bf1, acc1, 0, 0, 0);
                    }

                float v0 = fmaxf(fmaxf(fmaxf(acc0[0], acc0[1]), fmaxf(acc0[2], acc0[3])) + b2v0, 0.0f);
                float v1 = fmaxf(fmaxf(fmaxf(acc1[0], acc1[1]), fmaxf(acc1[2], acc1[3])) + b2v1, 0.0f);
                int mtg = c * 18 + mtl;
                pg[(mtg * 2 + p) * 64 + lane] = (unsigned)f2bf(v0) | ((unsigned)f2bf(v1) << 16);
            }
        }
    }
}

// fc1: bf16 MFMA split-K GEMM (exact round-3 kernel, replay-stable).
#define FC1_SPLIT 16
#define FC1_CHUNK 576   // 9 BK-steps of 64

__launch_bounds__(512)
__global__ void k_fc1(const ushort* __restrict__ A,    // pooled bf16 [2048][9216]
                      const ushort* __restrict__ Wp,   // packed fc1_w bf16 [128][9216]
                      float* __restrict__ part) {      // [16][2048][128]
    __shared__ ushort As[128 * 64];
    __shared__ ushort Ws[128 * 64];
    char* Ac = (char*)As;
    char* Wc = (char*)Ws;

    const int t = threadIdx.x;
    const int lane = t & 63;
    const int wv = t >> 6;
    const int wm = wv >> 2;        // 0..1
    const int wn = wv & 3;         // 0..3
    const int lr = lane & 15;
    const int lk = lane >> 4;
    const int m0 = blockIdx.x * 128;
    const int kc0 = blockIdx.y * FC1_CHUNK;

    const int trow = t >> 2;       // 0..127
    const int seg = t & 3;         // 0..3
    const int wb0 = trow * 128 + seg * 32;
    const int sw = (trow & 7) << 4;

    const ushort* Ab = A + (size_t)(m0 + trow) * 9216 + kc0 + seg * 16;
    const ushort* Wb = Wp + (size_t)trow * 9216 + kc0 + seg * 16;

    f32x4 acc[4][2];
    #pragma unroll
    for (int mf = 0; mf < 4; mf++)
        #pragma unroll
        for (int nf = 0; nf < 2; nf++) acc[mf][nf] = (f32x4){0.f, 0.f, 0.f, 0.f};

    short8 ra0 = *(const short8*)(Ab);
    short8 ra1 = *(const short8*)(Ab + 8);
    short8 rw0 = *(const short8*)(Wb);
    short8 rw1 = *(const short8*)(Wb + 8);
    short8 na0, na1, nw0, nw1;

    for (int s = 0; s < 9; s++) {
        *(short8*)(Ac + (wb0 ^ sw)) = ra0;
        *(short8*)(Ac + ((wb0 + 16) ^ sw)) = ra1;
        *(short8*)(Wc + (wb0 ^ sw)) = rw0;
        *(short8*)(Wc + ((wb0 + 16) ^ sw)) = rw1;
        __syncthreads();
        if (s < 8) {
            const ushort* An = Ab + (s + 1) * 64;
            const ushort* Wn = Wb + (s + 1) * 64;
            na0 = *(const short8*)(An);
            na1 = *(const short8*)(An + 8);
            nw0 = *(const short8*)(Wn);
            nw1 = *(const short8*)(Wn + 8);
        }
        #pragma unroll
        for (int ks = 0; ks < 2; ks++) {
            short8 af[4], bfr2[2];
            #pragma unroll
            for (int mf = 0; mf < 4; mf++) {
                int r = wm * 64 + mf * 16 + lr;
                af[mf] = *(const short8*)(Ac + ((r * 128 + ks * 64 + lk * 16) ^ ((r & 7) << 4)));
            }
            #pragma unroll
            for (int nf = 0; nf < 2; nf++) {
                int n = wn * 32 + nf * 16 + lr;
                bfr2[nf] = *(const short8*)(Wc + ((n * 128 + ks * 64 + lk * 16) ^ ((n & 7) << 4)));
            }
            #pragma unroll
            for (int mf = 0; mf < 4; mf++)
                #pragma unroll
                for (int nf = 0; nf < 2; nf++)
                    acc[mf][nf] = __builtin_amdgcn_mfma_f32_16x16x32_bf16(af[mf], bfr2[nf], acc[mf][nf], 0, 0, 0);
        }
        __syncthreads();
        if (s < 8) { ra0 = na0; ra1 = na1; rw0 = nw0; rw1 = nw1; }
    }

    float* pb = part + (size_t)blockIdx.y * (2048 * 128);
    #pragma unroll
    for (int mf = 0; mf < 4; mf++)
        #pragma unroll
        for (int nf = 0; nf < 2; nf++) {
            int mrow = m0 + wm * 64 + mf * 16 + lk * 4;
            int ncol = wn * 32 + nf * 16 + lr;
            #pragma unroll
            for (int q = 0; q < 4; q++)
                pb[(size_t)(mrow + q) * 128 + ncol] = acc[mf][nf][q];
        }
}

// fc2: reduce split-K partials + fc1 bias + relu, then 128->10 GEMV.
__global__ void k_fc2(const float* __restrict__ part,   // [16][2048][128]
                      const float* __restrict__ fc1_b,
                      const float* __restrict__ fc2_w,  // [10][128]
                      const float* __restrict__ fc2_b,
                      float* __restrict__ out) {        // [2048][10]
    __shared__ float hs[16 * 128];
    __shared__ float wsm[10 * 128];
    __shared__ float bsm[10];
    const int t = threadIdx.x;
    const int m0 = blockIdx.x * 16;
    for (int i = t; i < 1280; i += 256) wsm[i] = fc2_w[i];
    if (t < 10) bsm[t] = fc2_b[t];
    #pragma unroll
    for (int e = 0; e < 8; e++) {
        int i = t + e * 256;
        int r = i >> 7, c = i & 127;
        float s = fc1_b[c];
        #pragma unroll
        for (int kc = 0; kc < FC1_SPLIT; kc++)
            s += part[(size_t)kc * (2048 * 128) + (size_t)(m0 + r) * 128 + c];
        hs[i] = fmaxf(s, 0.0f);
    }
    __syncthreads();
    int r = t / 16, c = t % 16;
    if (c < 10) {
        float s = bsm[c];
        const float* hp = &hs[r * 128];
        const float* wp = &wsm[c * 128];
        #pragma unroll
        for (int k = 0; k < 128; k++) s = fmaf(hp[k], wp[k], s);
        out[(size_t)(m0 + r) * 10 + c] = s;
    }
}

extern "C" void kernel_launch(void* const* d_in, const int* in_sizes, int n_in,
                              void* d_out, int out_size, void* d_ws, size_t ws_size,
                              hipStream_t stream) {
    const float* x     = (const float*)d_in[0];
    const float* w1    = (const float*)d_in[1];
    const float* b1    = (const float*)d_in[2];
    const float* w2    = (const float*)d_in[3];
    const float* b2    = (const float*)d_in[4];
    const float* fc1_w = (const float*)d_in[5];
    const float* fc1_b = (const float*)d_in[6];
    const float* fc2_w = (const float*)d_in[7];
    const float* fc2_b = (const float*)d_in[8];
    float* out = (float*)d_out;

    char* wsb = (char*)d_ws;
    ushort* bfr    = (ushort*)wsb;                       // 36864 B
    ushort* wp     = (ushort*)(wsb + 36864);             // 2359296 B
    ushort* pooled = (ushort*)(wsb + 2396160);           // 37748736 B
    float*  part   = (float*)(wsb + 40144896);           // 16777216 B

    k_w2pack<<<72, 256, 0, stream>>>(w2, bfr);
    k_fc1wpack<<<4608, 256, 0, stream>>>(fc1_w, wp);
    k_conv_fused<<<NIMG, 512, 0, stream>>>(x, w1, b1, bfr, b2, pooled);
    k_fc1<<<dim3(16, FC1_SPLIT), 512, 0, stream>>>(pooled, wp, part);
    k_fc2<<<NIMG / 16, 256, 0, stream>>>(part, fc1_b, fc2_w, fc2_b, out);
}

// Round 8
// 172.218 us; speedup vs baseline: 2.0637x; 2.0637x over previous
//
#include <hip/hip_runtime.h>
#include <stddef.h>

// ---------------------------------------------------------------------------
// CustomNet forward. Round 8: round-7 chunked-LDS conv with the launch_bounds
// poison removed (r7: (512,8) forced VGPR=32 -> 625MB scratch spill).
//  - conv: round-3 wave decomposition, h1 chunked into two 14-row halves
//    (LDS 26.4KB, 4 blocks/CU thread-capped), XOR-swizzled h1, w1/b1 reloaded
//    per chunk to keep register live-ranges phase-local.
//  - fc1/fc2: byte-identical round-3 kernels (replay-proven).
// ---------------------------------------------------------------------------

#define NIMG 2048

typedef __attribute__((ext_vector_type(8))) short short8;
typedef __attribute__((ext_vector_type(4))) float f32x4;

__device__ inline ushort f2bf(float f) {
    unsigned u = __builtin_bit_cast(unsigned, f);
    unsigned r = (u + 0x7fff + ((u >> 16) & 1)) >> 16;   // RTNE, finite
    return (ushort)r;
}

// pack w2 [64][32][3][3] into per-lane 16x16x32 MFMA B-fragments (round-3):
// bfr[((nt*9 + kyx)*64 + lane)*8 + j] = bf16(w2[oc=nt*16+(lane&15)][ic=8*(lane>>4)+j][kyx])
__global__ void k_w2pack(const float* __restrict__ w2, ushort* __restrict__ bfr) {
    int i = blockIdx.x * 256 + threadIdx.x;
    if (i < 18432) {
        int j = i & 7;
        int l = (i >> 3) & 63;
        int t = i >> 9;
        int kyx = t % 9, nt = t / 9;
        int oc = nt * 16 + (l & 15);
        int ic = 8 * (l >> 4) + j;
        bfr[i] = f2bf(w2[oc * 288 + ic * 9 + kyx]);
    }
}

// Permute fc1_w columns into the conv kernel's pooled output order (bf16).
// kp = ((mt*2 + p)*64 + lane)*2 + j ->
//   oc = (2p+j)*16 + (lane&15); qid = mt*4 + (lane>>4); orig_k = oc*144 + qid.
__global__ void k_fc1wpack(const float* __restrict__ fc1_w, ushort* __restrict__ wp) {
    int idx = blockIdx.x * 256 + threadIdx.x;
    if (idx < 128 * 9216) {
        int n = idx / 9216, kp = idx % 9216;
        int j = kp & 1;
        int lane = (kp >> 1) & 63;
        int word = kp >> 7;
        int p = word & 1;
        int mt = word >> 1;
        int oc = (2 * p + j) * 16 + (lane & 15);
        int qid = mt * 4 + (lane >> 4);
        wp[idx] = f2bf(fc1_w[(size_t)n * 9216 + oc * 144 + qid]);
    }
}

// swizzled h1-chunk byte address for (local position q in [0,364), 16B-group g)
#define SWZB(q, g) ((((q) << 6) | ((g) << 4)) ^ (((q) & 14) << 3))

// LDS: [0, 23296) h1 chunk (14 rows x 26 pos x 32 ic bf16, swizzled);
//      [23296, 26432) xs (784 f32).
__launch_bounds__(512)
__global__ void k_conv_fused(const float* __restrict__ x,
                             const float* __restrict__ w1,
                             const float* __restrict__ b1,
                             const ushort* __restrict__ bfr,
                             const float* __restrict__ b2,
                             ushort* __restrict__ pooled) {   // bf16, permuted k
    __shared__ char smem[26432];
    float* xs = (float*)(smem + 23296);
    const int tid = threadIdx.x;
    const int img = blockIdx.x;
    const int lane = tid & 63;
    const int w = tid >> 6;

    // ---- stage x ----
    const float* xg = x + (size_t)img * 784;
    for (int i = tid; i < 784; i += 512) xs[i] = xg[i];

    const int ocg = tid & 3;
    const int p = w & 1;          // oc-tile pair
    const int g = w >> 1;         // m-group
    const int row = lane & 15;
    const int ic8 = lane >> 4;
    float b2v0 = b2[(2 * p) * 16 + row];
    float b2v1 = b2[(2 * p + 1) * 16 + row];
    uint* pg = (uint*)(pooled + (size_t)img * 9216);

    __syncthreads();   // xs ready

    #pragma unroll 1
    for (int c = 0; c < 2; c++) {
        if (c) __syncthreads();   // chunk-0 readers done before overwrite

        // ---- conv1 weights/bias (reloaded per chunk: phase-local live range) ----
        float w1r[72], b1r[8];
        #pragma unroll
        for (int j = 0; j < 8; j++) {
            b1r[j] = b1[ocg * 8 + j];
            #pragma unroll
            for (int q = 0; q < 9; q++) w1r[j * 9 + q] = w1[(ocg * 8 + j) * 9 + q];
        }

        // ---- conv1 + relu -> swizzled h1 chunk (rows c*12 .. c*12+13) ----
        #pragma unroll
        for (int it = 0; it < 2; it++) {
            int pid = (tid >> 2) + it * 128;
            if (pid < 182) {
                int ry = pid / 13;
                int px2 = (pid - ry * 13) * 2;
                const float* xr = &xs[(c * 12 + ry) * 28 + px2];
                float xv[3][4];
                #pragma unroll
                for (int r = 0; r < 3; r++) {
                    float2 u = *(const float2*)&xr[r * 28];
                    float2 v = *(const float2*)&xr[r * 28 + 2];
                    xv[r][0] = u.x; xv[r][1] = u.y; xv[r][2] = v.x; xv[r][3] = v.y;
                }
                short8 pk0, pk1;
                #pragma unroll
                for (int j = 0; j < 8; j++) {
                    float s0 = b1r[j], s1 = b1r[j];
                    #pragma unroll
                    for (int ky = 0; ky < 3; ky++)
                        #pragma unroll
                        for (int kx = 0; kx < 3; kx++) {
                            float wv = w1r[j * 9 + ky * 3 + kx];
                            s0 = fmaf(wv, xv[ky][kx], s0);
                            s1 = fmaf(wv, xv[ky][kx + 1], s1);
                        }
                    pk0[j] = (short)f2bf(fmaxf(s0, 0.0f));
                    pk1[j] = (short)f2bf(fmaxf(s1, 0.0f));
                }
                int q0 = ry * 26 + px2;
                *(short8*)(smem + SWZB(q0, ocg)) = pk0;
                *(short8*)(smem + SWZB(q0 + 1, ocg)) = pk1;
            }
        }
        __syncthreads();

        // ---- conv2 MFMA on this chunk (18 local m-tiles) ----
        #pragma unroll 1
        for (int i = 0; i < 5; i++) {
            int mtl = g + 4 * i;
            if (mtl < 18) {
                int m = mtl * 16 + row;          // A-fragment row for this lane
                int qidl = m >> 2, de = m & 3;
                int py = qidl / 12, px = qidl - py * 12;
                int ql = (2 * py + (de >> 1)) * 26 + 2 * px + (de & 1);

                f32x4 acc0 = {0.f, 0.f, 0.f, 0.f};
                f32x4 acc1 = {0.f, 0.f, 0.f, 0.f};
                #pragma unroll
                for (int ky = 0; ky < 3; ky++)
                    #pragma unroll
                    for (int kx = 0; kx < 3; kx++) {
                        const int kyx = ky * 3 + kx;
                        short8 a = *(const short8*)(smem + SWZB(ql + ky * 26 + kx, ic8));
                        short8 bf0 = *(const short8*)&bfr[(((2 * p) * 9 + kyx) * 64 + lane) * 8];
                        short8 bf1 = *(const short8*)&bfr[(((2 * p + 1) * 9 + kyx) * 64 + lane) * 8];
                        acc0 = __builtin_amdgcn_mfma_f32_16x16x32_bf16(a, bf0, acc0, 0, 0, 0);
                        acc1 = __builtin_amdgcn_mfma_f32_16x16x32_bf16(a, bf1, acc1, 0, 0, 0);
                    }

                float v0 = fmaxf(fmaxf(fmaxf(acc0[0], acc0[1]), fmaxf(acc0[2], acc0[3])) + b2v0, 0.0f);
                float v1 = fmaxf(fmaxf(fmaxf(acc1[0], acc1[1]), fmaxf(acc1[2], acc1[3])) + b2v1, 0.0f);
                int mtg = c * 18 + mtl;
                pg[(mtg * 2 + p) * 64 + lane] = (unsigned)f2bf(v0) | ((unsigned)f2bf(v1) << 16);
            }
        }
    }
}

// fc1: bf16 MFMA split-K GEMM (exact round-3 kernel, replay-stable).
#define FC1_SPLIT 16
#define FC1_CHUNK 576   // 9 BK-steps of 64

__launch_bounds__(512)
__global__ void k_fc1(const ushort* __restrict__ A,    // pooled bf16 [2048][9216]
                      const ushort* __restrict__ Wp,   // packed fc1_w bf16 [128][9216]
                      float* __restrict__ part) {      // [16][2048][128]
    __shared__ ushort As[128 * 64];
    __shared__ ushort Ws[128 * 64];
    char* Ac = (char*)As;
    char* Wc = (char*)Ws;

    const int t = threadIdx.x;
    const int lane = t & 63;
    const int wv = t >> 6;
    const int wm = wv >> 2;        // 0..1
    const int wn = wv & 3;         // 0..3
    const int lr = lane & 15;
    const int lk = lane >> 4;
    const int m0 = blockIdx.x * 128;
    const int kc0 = blockIdx.y * FC1_CHUNK;

    const int trow = t >> 2;       // 0..127
    const int seg = t & 3;         // 0..3
    const int wb0 = trow * 128 + seg * 32;
    const int sw = (trow & 7) << 4;

    const ushort* Ab = A + (size_t)(m0 + trow) * 9216 + kc0 + seg * 16;
    const ushort* Wb = Wp + (size_t)trow * 9216 + kc0 + seg * 16;

    f32x4 acc[4][2];
    #pragma unroll
    for (int mf = 0; mf < 4; mf++)
        #pragma unroll
        for (int nf = 0; nf < 2; nf++) acc[mf][nf] = (f32x4){0.f, 0.f, 0.f, 0.f};

    short8 ra0 = *(const short8*)(Ab);
    short8 ra1 = *(const short8*)(Ab + 8);
    short8 rw0 = *(const short8*)(Wb);
    short8 rw1 = *(const short8*)(Wb + 8);
    short8 na0, na1, nw0, nw1;

    for (int s = 0; s < 9; s++) {
        *(short8*)(Ac + (wb0 ^ sw)) = ra0;
        *(short8*)(Ac + ((wb0 + 16) ^ sw)) = ra1;
        *(short8*)(Wc + (wb0 ^ sw)) = rw0;
        *(short8*)(Wc + ((wb0 + 16) ^ sw)) = rw1;
        __syncthreads();
        if (s < 8) {
            const ushort* An = Ab + (s + 1) * 64;
            const ushort* Wn = Wb + (s + 1) * 64;
            na0 = *(const short8*)(An);
            na1 = *(const short8*)(An + 8);
            nw0 = *(const short8*)(Wn);
            nw1 = *(const short8*)(Wn + 8);
        }
        #pragma unroll
        for (int ks = 0; ks < 2; ks++) {
            short8 af[4], bfr2[2];
            #pragma unroll
            for (int mf = 0; mf < 4; mf++) {
                int r = wm * 64 + mf * 16 + lr;
                af[mf] = *(const short8*)(Ac + ((r * 128 + ks * 64 + lk * 16) ^ ((r & 7) << 4)));
            }
            #pragma unroll
            for (int nf = 0; nf < 2; nf++) {
                int n = wn * 32 + nf * 16 + lr;
                bfr2[nf] = *(const short8*)(Wc + ((n * 128 + ks * 64 + lk * 16) ^ ((n & 7) << 4)));
            }
            #pragma unroll
            for (int mf = 0; mf < 4; mf++)
                #pragma unroll
                for (int nf = 0; nf < 2; nf++)
                    acc[mf][nf] = __builtin_amdgcn_mfma_f32_16x16x32_bf16(af[mf], bfr2[nf], acc[mf][nf], 0, 0, 0);
        }
        __syncthreads();
        if (s < 8) { ra0 = na0; ra1 = na1; rw0 = nw0; rw1 = nw1; }
    }

    float* pb = part + (size_t)blockIdx.y * (2048 * 128);
    #pragma unroll
    for (int mf = 0; mf < 4; mf++)
        #pragma unroll
        for (int nf = 0; nf < 2; nf++) {
            int mrow = m0 + wm * 64 + mf * 16 + lk * 4;
            int ncol = wn * 32 + nf * 16 + lr;
            #pragma unroll
            for (int q = 0; q < 4; q++)
                pb[(size_t)(mrow + q) * 128 + ncol] = acc[mf][nf][q];
        }
}

// fc2: reduce split-K partials + fc1 bias + relu, then 128->10 GEMV.
__global__ void k_fc2(const float* __restrict__ part,   // [16][2048][128]
                      const float* __restrict__ fc1_b,
                      const float* __restrict__ fc2_w,  // [10][128]
                      const float* __restrict__ fc2_b,
                      float* __restrict__ out) {        // [2048][10]
    __shared__ float hs[16 * 128];
    __shared__ float wsm[10 * 128];
    __shared__ float bsm[10];
    const int t = threadIdx.x;
    const int m0 = blockIdx.x * 16;
    for (int i = t; i < 1280; i += 256) wsm[i] = fc2_w[i];
    if (t < 10) bsm[t] = fc2_b[t];
    #pragma unroll
    for (int e = 0; e < 8; e++) {
        int i = t + e * 256;
        int r = i >> 7, c = i & 127;
        float s = fc1_b[c];
        #pragma unroll
        for (int kc = 0; kc < FC1_SPLIT; kc++)
            s += part[(size_t)kc * (2048 * 128) + (size_t)(m0 + r) * 128 + c];
        hs[i] = fmaxf(s, 0.0f);
    }
    __syncthreads();
    int r = t / 16, c = t % 16;
    if (c < 10) {
        float s = bsm[c];
        const float* hp = &hs[r * 128];
        const float* wp = &wsm[c * 128];
        #pragma unroll
        for (int k = 0; k < 128; k++) s = fmaf(hp[k], wp[k], s);
        out[(size_t)(m0 + r) * 10 + c] = s;
    }
}

extern "C" void kernel_launch(void* const* d_in, const int* in_sizes, int n_in,
                              void* d_out, int out_size, void* d_ws, size_t ws_size,
                              hipStream_t stream) {
    const float* x     = (const float*)d_in[0];
    const float* w1    = (const float*)d_in[1];
    const float* b1    = (const float*)d_in[2];
    const float* w2    = (const float*)d_in[3];
    const float* b2    = (const float*)d_in[4];
    const float* fc1_w = (const float*)d_in[5];
    const float* fc1_b = (const float*)d_in[6];
    const float* fc2_w = (const float*)d_in[7];
    const float* fc2_b = (const float*)d_in[8];
    float* out = (float*)d_out;

    char* wsb = (char*)d_ws;
    ushort* bfr    = (ushort*)wsb;                       // 36864 B
    ushort* wp     = (ushort*)(wsb + 36864);             // 2359296 B
    ushort* pooled = (ushort*)(wsb + 2396160);           // 37748736 B
    float*  part   = (float*)(wsb + 40144896);           // 16777216 B

    k_w2pack<<<72, 256, 0, stream>>>(w2, bfr);
    k_fc1wpack<<<4608, 256, 0, stream>>>(fc1_w, wp);
    k_conv_fused<<<NIMG, 512, 0, stream>>>(x, w1, b1, bfr, b2, pooled);
    k_fc1<<<dim3(16, FC1_SPLIT), 512, 0, stream>>>(pooled, wp, part);
    k_fc2<<<NIMG / 16, 256, 0, stream>>>(part, fc1_b, fc2_w, fc2_b, out);
}

// Round 9
// 99.726 us; speedup vs baseline: 3.5639x; 1.7269x over previous
//
#include <hip/hip_runtime.h>
#include <stddef.h>

// ---------------------------------------------------------------------------
// CustomNet forward. Round 9 = round 3 (best: 93 us) + ONE change:
// XOR-swizzled h1p LDS layout (SWZB) in the conv kernel, store+read sides.
// Everything else byte-identical to round 3 (fc1/fc2/packs replay-proven).
// ---------------------------------------------------------------------------

#define NIMG 2048

typedef __attribute__((ext_vector_type(8))) short short8;
typedef __attribute__((ext_vector_type(4))) float f32x4;

__device__ inline ushort f2bf(float f) {
    unsigned u = __builtin_bit_cast(unsigned, f);
    unsigned r = (u + 0x7fff + ((u >> 16) & 1)) >> 16;   // RTNE, finite
    return (ushort)r;
}

// pack w2 [64][32][3][3] into per-lane MFMA B-fragments:
// bfr[((nt*9 + kyx)*64 + lane)*8 + j] = bf16(w2[oc=nt*16+(lane&15)][ic=8*(lane>>4)+j][kyx])
__global__ void k_w2pack(const float* __restrict__ w2, ushort* __restrict__ bfr) {
    int i = blockIdx.x * 256 + threadIdx.x;
    if (i < 18432) {
        int j = i & 7;
        int l = (i >> 3) & 63;
        int t = i >> 9;
        int kyx = t % 9, nt = t / 9;
        int oc = nt * 16 + (l & 15);
        int ic = 8 * (l >> 4) + j;
        bfr[i] = f2bf(w2[oc * 288 + ic * 9 + kyx]);
    }
}

// Permute fc1_w columns into the conv kernel's pooled output order (round-3).
// kp = ((wv*9+i)*64+lane)*2 + j  ->
//   oc=(2*(wv&1)+j)*16+(lane&15); mt=(wv>>1)+i*4; qid=mt*4+(lane>>4);
//   orig_k = oc*144 + qid.
__global__ void k_fc1wpack(const float* __restrict__ fc1_w, ushort* __restrict__ wp) {
    int idx = blockIdx.x * 256 + threadIdx.x;
    if (idx < 128 * 9216) {
        int n = idx / 9216, kp = idx % 9216;
        int j = kp & 1;
        int lane = (kp >> 1) & 63;
        int t = kp >> 7;
        int i = t % 9, wv = t / 9;
        int oc = (2 * (wv & 1) + j) * 16 + (lane & 15);
        int mt = (wv >> 1) + i * 4;
        int qid = mt * 4 + (lane >> 4);
        wp[idx] = f2bf(fc1_w[(size_t)n * 9216 + oc * 144 + qid]);
    }
}

// swizzled h1p byte address for (position q in [0,676), 16B-group g in [0,4))
#define SWZB(q, g) ((((q) << 6) | ((g) << 4)) ^ (((q) & 14) << 3))

// LDS: h1p (676 pos x 32 ic bf16, swizzled) = 43264 B, xs (784 f32) = 3136 B.
__launch_bounds__(512)
__global__ void k_conv_fused(const float* __restrict__ x,
                             const float* __restrict__ w1,
                             const float* __restrict__ b1,
                             const ushort* __restrict__ bfr,
                             const float* __restrict__ b2,
                             ushort* __restrict__ pooled) {   // bf16, permuted k
    __shared__ char smem[46400];
    float* xs = (float*)(smem + 43264);
    const int tid = threadIdx.x;
    const int img = blockIdx.x;
    const int lane = tid & 63;
    const int w = tid >> 6;

    // ---- stage x ----
    const float* xg = x + (size_t)img * 784;
    for (int i = tid; i < 784; i += 512) xs[i] = xg[i];

    // ---- conv1 weights/bias in registers (ocg fixed per thread) ----
    const int ocg = tid & 3;
    float w1r[72], b1r[8];
    #pragma unroll
    for (int j = 0; j < 8; j++) {
        b1r[j] = b1[ocg * 8 + j];
        #pragma unroll
        for (int q = 0; q < 9; q++) w1r[j * 9 + q] = w1[(ocg * 8 + j) * 9 + q];
    }
    __syncthreads();

    // ---- conv1 + relu -> swizzled h1p[pos][ic] bf16 (pos-pairs) ----
    #pragma unroll
    for (int it = 0; it < 3; it++) {
        int pid = (tid >> 2) + it * 128;
        if (pid < 338) {
            int y = pid / 13;
            int px2 = (pid - y * 13) * 2;
            const float* xr = &xs[y * 28 + px2];
            float xv[3][4];
            #pragma unroll
            for (int r = 0; r < 3; r++) {
                float2 u = *(const float2*)&xr[r * 28];
                float2 v = *(const float2*)&xr[r * 28 + 2];
                xv[r][0] = u.x; xv[r][1] = u.y; xv[r][2] = v.x; xv[r][3] = v.y;
            }
            short8 pk0, pk1;
            #pragma unroll
            for (int j = 0; j < 8; j++) {
                float s0 = b1r[j], s1 = b1r[j];
                #pragma unroll
                for (int ky = 0; ky < 3; ky++)
                    #pragma unroll
                    for (int kx = 0; kx < 3; kx++) {
                        float wv = w1r[j * 9 + ky * 3 + kx];
                        s0 = fmaf(wv, xv[ky][kx], s0);
                        s1 = fmaf(wv, xv[ky][kx + 1], s1);
                    }
                pk0[j] = (short)f2bf(fmaxf(s0, 0.0f));
                pk1[j] = (short)f2bf(fmaxf(s1, 0.0f));
            }
            int pos0 = y * 26 + px2;
            *(short8*)(smem + SWZB(pos0, ocg)) = pk0;
            *(short8*)(smem + SWZB(pos0 + 1, ocg)) = pk1;
        }
    }
    __syncthreads();

    // ---- conv2 MFMA + in-lane maxpool + direct permuted bf16 store ----
    const int p = w & 1;
    const int g = w >> 1;

    short8 bf[2][9];
    #pragma unroll
    for (int j = 0; j < 2; j++)
        #pragma unroll
        for (int kyx = 0; kyx < 9; kyx++)
            bf[j][kyx] = *(const short8*)&bfr[(((2 * p + j) * 9 + kyx) * 64 + lane) * 8];

    const int row = lane & 15;
    const int ic8 = lane >> 4;
    float b2v[2];
    b2v[0] = b2[(2 * p) * 16 + row];
    b2v[1] = b2[(2 * p + 1) * 16 + row];

    unsigned* pp = (unsigned*)(pooled + (size_t)img * 9216);

    #pragma unroll 1
    for (int i = 0; i < 9; i++) {
        int mt = g + i * 4;
        int m = mt * 16 + row;
        int qid = m >> 2;
        int de = m & 3;
        int py = qid / 12, px = qid - py * 12;
        int yy = py * 2 + (de >> 1);
        int xx2 = px * 2 + (de & 1);
        int pos = yy * 26 + xx2;

        f32x4 acc0 = {0.f, 0.f, 0.f, 0.f};
        f32x4 acc1 = {0.f, 0.f, 0.f, 0.f};
        #pragma unroll
        for (int ky = 0; ky < 3; ky++)
            #pragma unroll
            for (int kx = 0; kx < 3; kx++) {
                int q = pos + ky * 26 + kx;
                short8 a = *(const short8*)(smem + SWZB(q, ic8));
                acc0 = __builtin_amdgcn_mfma_f32_16x16x32_bf16(a, bf[0][ky * 3 + kx], acc0, 0, 0, 0);
                acc1 = __builtin_amdgcn_mfma_f32_16x16x32_bf16(a, bf[1][ky * 3 + kx], acc1, 0, 0, 0);
            }
        float v0 = fmaxf(fmaxf(fmaxf(acc0[0], acc0[1]), fmaxf(acc0[2], acc0[3])) + b2v[0], 0.0f);
        float v1 = fmaxf(fmaxf(fmaxf(acc1[0], acc1[1]), fmaxf(acc1[2], acc1[3])) + b2v[1], 0.0f);
        pp[(w * 9 + i) * 64 + lane] = (unsigned)f2bf(v0) | ((unsigned)f2bf(v1) << 16);
    }
}

// fc1: bf16 MFMA split-K GEMM (exact round-3 kernel, replay-stable).
#define FC1_SPLIT 16
#define FC1_CHUNK 576   // 9 BK-steps of 64

__launch_bounds__(512)
__global__ void k_fc1(const ushort* __restrict__ A,    // pooled bf16 [2048][9216]
                      const ushort* __restrict__ Wp,   // packed fc1_w bf16 [128][9216]
                      float* __restrict__ part) {      // [16][2048][128]
    __shared__ ushort As[128 * 64];
    __shared__ ushort Ws[128 * 64];
    char* Ac = (char*)As;
    char* Wc = (char*)Ws;

    const int t = threadIdx.x;
    const int lane = t & 63;
    const int wv = t >> 6;
    const int wm = wv >> 2;        // 0..1
    const int wn = wv & 3;         // 0..3
    const int lr = lane & 15;
    const int lk = lane >> 4;
    const int m0 = blockIdx.x * 128;
    const int kc0 = blockIdx.y * FC1_CHUNK;

    const int trow = t >> 2;       // 0..127
    const int seg = t & 3;         // 0..3
    const int wb0 = trow * 128 + seg * 32;
    const int sw = (trow & 7) << 4;

    const ushort* Ab = A + (size_t)(m0 + trow) * 9216 + kc0 + seg * 16;
    const ushort* Wb = Wp + (size_t)trow * 9216 + kc0 + seg * 16;

    f32x4 acc[4][2];
    #pragma unroll
    for (int mf = 0; mf < 4; mf++)
        #pragma unroll
        for (int nf = 0; nf < 2; nf++) acc[mf][nf] = (f32x4){0.f, 0.f, 0.f, 0.f};

    short8 ra0 = *(const short8*)(Ab);
    short8 ra1 = *(const short8*)(Ab + 8);
    short8 rw0 = *(const short8*)(Wb);
    short8 rw1 = *(const short8*)(Wb + 8);
    short8 na0, na1, nw0, nw1;

    for (int s = 0; s < 9; s++) {
        *(short8*)(Ac + (wb0 ^ sw)) = ra0;
        *(short8*)(Ac + ((wb0 + 16) ^ sw)) = ra1;
        *(short8*)(Wc + (wb0 ^ sw)) = rw0;
        *(short8*)(Wc + ((wb0 + 16) ^ sw)) = rw1;
        __syncthreads();
        if (s < 8) {
            const ushort* An = Ab + (s + 1) * 64;
            const ushort* Wn = Wb + (s + 1) * 64;
            na0 = *(const short8*)(An);
            na1 = *(const short8*)(An + 8);
            nw0 = *(const short8*)(Wn);
            nw1 = *(const short8*)(Wn + 8);
        }
        #pragma unroll
        for (int ks = 0; ks < 2; ks++) {
            short8 af[4], bfr2[2];
            #pragma unroll
            for (int mf = 0; mf < 4; mf++) {
                int r = wm * 64 + mf * 16 + lr;
                af[mf] = *(const short8*)(Ac + ((r * 128 + ks * 64 + lk * 16) ^ ((r & 7) << 4)));
            }
            #pragma unroll
            for (int nf = 0; nf < 2; nf++) {
                int n = wn * 32 + nf * 16 + lr;
                bfr2[nf] = *(const short8*)(Wc + ((n * 128 + ks * 64 + lk * 16) ^ ((n & 7) << 4)));
            }
            #pragma unroll
            for (int mf = 0; mf < 4; mf++)
                #pragma unroll
                for (int nf = 0; nf < 2; nf++)
                    acc[mf][nf] = __builtin_amdgcn_mfma_f32_16x16x32_bf16(af[mf], bfr2[nf], acc[mf][nf], 0, 0, 0);
        }
        __syncthreads();
        if (s < 8) { ra0 = na0; ra1 = na1; rw0 = nw0; rw1 = nw1; }
    }

    float* pb = part + (size_t)blockIdx.y * (2048 * 128);
    #pragma unroll
    for (int mf = 0; mf < 4; mf++)
        #pragma unroll
        for (int nf = 0; nf < 2; nf++) {
            int mrow = m0 + wm * 64 + mf * 16 + lk * 4;
            int ncol = wn * 32 + nf * 16 + lr;
            #pragma unroll
            for (int q = 0; q < 4; q++)
                pb[(size_t)(mrow + q) * 128 + ncol] = acc[mf][nf][q];
        }
}

// fc2: reduce split-K partials + fc1 bias + relu, then 128->10 GEMV.
__global__ void k_fc2(const float* __restrict__ part,   // [16][2048][128]
                      const float* __restrict__ fc1_b,
                      const float* __restrict__ fc2_w,  // [10][128]
                      const float* __restrict__ fc2_b,
                      float* __restrict__ out) {        // [2048][10]
    __shared__ float hs[16 * 128];
    __shared__ float wsm[10 * 128];
    __shared__ float bsm[10];
    const int t = threadIdx.x;
    const int m0 = blockIdx.x * 16;
    for (int i = t; i < 1280; i += 256) wsm[i] = fc2_w[i];
    if (t < 10) bsm[t] = fc2_b[t];
    #pragma unroll
    for (int e = 0; e < 8; e++) {
        int i = t + e * 256;
        int r = i >> 7, c = i & 127;
        float s = fc1_b[c];
        #pragma unroll
        for (int kc = 0; kc < FC1_SPLIT; kc++)
            s += part[(size_t)kc * (2048 * 128) + (size_t)(m0 + r) * 128 + c];
        hs[i] = fmaxf(s, 0.0f);
    }
    __syncthreads();
    int r = t / 16, c = t % 16;
    if (c < 10) {
        float s = bsm[c];
        const float* hp = &hs[r * 128];
        const float* wp = &wsm[c * 128];
        #pragma unroll
        for (int k = 0; k < 128; k++) s = fmaf(hp[k], wp[k], s);
        out[(size_t)(m0 + r) * 10 + c] = s;
    }
}

extern "C" void kernel_launch(void* const* d_in, const int* in_sizes, int n_in,
                              void* d_out, int out_size, void* d_ws, size_t ws_size,
                              hipStream_t stream) {
    const float* x     = (const float*)d_in[0];
    const float* w1    = (const float*)d_in[1];
    const float* b1    = (const float*)d_in[2];
    const float* w2    = (const float*)d_in[3];
    const float* b2    = (const float*)d_in[4];
    const float* fc1_w = (const float*)d_in[5];
    const float* fc1_b = (const float*)d_in[6];
    const float* fc2_w = (const float*)d_in[7];
    const float* fc2_b = (const float*)d_in[8];
    float* out = (float*)d_out;

    char* wsb = (char*)d_ws;
    ushort* bfr    = (ushort*)wsb;                       // 36864 B
    ushort* wp     = (ushort*)(wsb + 36864);             // 2359296 B
    ushort* pooled = (ushort*)(wsb + 2396160);           // 37748736 B
    float*  part   = (float*)(wsb + 40144896);           // 16777216 B

    k_w2pack<<<72, 256, 0, stream>>>(w2, bfr);
    k_fc1wpack<<<4608, 256, 0, stream>>>(fc1_w, wp);
    k_conv_fused<<<NIMG, 512, 0, stream>>>(x, w1, b1, bfr, b2, pooled);
    k_fc1<<<dim3(16, FC1_SPLIT), 512, 0, stream>>>(pooled, wp, part);
    k_fc2<<<NIMG / 16, 256, 0, stream>>>(part, fc1_b, fc2_w, fc2_b, out);
}